// Round 1
// baseline (1766.716 us; speedup 1.0000x reference)
//
#include <hip/hip_runtime.h>

// FiLM: LSTM(64, activation=sigmoid, recurrent_activation=sigmoid) + 2x Dense(1)
// B=256 batches -> 256 blocks (1 per CU). Block = 256 threads.
// Thread g owns gate-column g (of 4H=256): z[g] = b[g] + x_t . W[:,g] + h . U[:,g]
// W/U columns live in 128 VGPRs/thread. x staged in LDS 16-step chunks with
// register prefetch. h broadcast via LDS. Cell state c lives in threads 0..63.

constexpr int Bsz = 256;
constexpr int Tn  = 2048;
constexpr int Dn  = 64;
constexpr int Hn  = 64;
constexpr int G4  = 4 * Hn;   // 256
constexpr int CH  = 16;       // timestep chunk staged in LDS

__device__ __forceinline__ float fast_sigmoid(float z) {
    // 1/(1+exp(-z)); v_exp + v_rcp, plenty of precision for 2.2e-2 threshold
    return __builtin_amdgcn_rcpf(1.0f + __expf(-z));
}

__global__ __launch_bounds__(256, 1) void lstm_film_kernel(
    const float* __restrict__ x,     // [B,T,D]
    const float* __restrict__ W,     // [D,4H] row-major
    const float* __restrict__ U,     // [H,4H] row-major
    const float* __restrict__ bias,  // [4H]
    const float* __restrict__ wg,    // [H]
    const float* __restrict__ bgam,  // [1]
    const float* __restrict__ wb,    // [H]
    const float* __restrict__ bbet,  // [1]
    float* __restrict__ out)         // [2*B] : gamma[256] then beta[256]
{
    __shared__ float xs[CH * Dn];    // 4 KiB chunk of x for this batch
    __shared__ float h_lds[Hn];
    __shared__ float a_lds[G4];      // sigmoided gate values

    const int b = blockIdx.x;
    const int g = threadIdx.x;

    // Cache this thread's W/U column in registers (fully static indexing).
    float Wc[Dn];
    float Uc[Hn];
#pragma unroll
    for (int k = 0; k < Dn; ++k) Wc[k] = W[k * G4 + g];
#pragma unroll
    for (int k = 0; k < Hn; ++k) Uc[k] = U[k * G4 + g];
    const float bg = bias[g];

    float c = 0.0f;                  // thread j<64 owns c[j]
    if (g < Hn) h_lds[g] = 0.0f;

    const float* xb = x + (size_t)b * Tn * Dn;

    // Prefetch chunk 0 (each thread: one float4 of the 1024-float chunk).
    float4 xreg = ((const float4*)xb)[g];

    for (int t0 = 0; t0 < Tn; t0 += CH) {
        // Previous step's trailing barrier guarantees xs is no longer read.
        ((float4*)xs)[g] = xreg;
        __syncthreads();
        if (t0 + CH < Tn) {
            xreg = ((const float4*)(xb + (size_t)(t0 + CH) * Dn))[g];
        }

        for (int tt = 0; tt < CH; ++tt) {
            const float4* xt  = (const float4*)(xs + tt * Dn);
            const float4* hv4 = (const float4*)h_lds;
            float a0 = bg, a1 = 0.f, a2 = 0.f, a3 = 0.f;
#pragma unroll
            for (int k = 0; k < Dn / 4; ++k) {   // x . W[:,g]
                float4 xv = xt[k];
                a0 = fmaf(xv.x, Wc[4 * k + 0], a0);
                a1 = fmaf(xv.y, Wc[4 * k + 1], a1);
                a2 = fmaf(xv.z, Wc[4 * k + 2], a2);
                a3 = fmaf(xv.w, Wc[4 * k + 3], a3);
            }
#pragma unroll
            for (int k = 0; k < Hn / 4; ++k) {   // h . U[:,g]
                float4 hv = hv4[k];
                a0 = fmaf(hv.x, Uc[4 * k + 0], a0);
                a1 = fmaf(hv.y, Uc[4 * k + 1], a1);
                a2 = fmaf(hv.z, Uc[4 * k + 2], a2);
                a3 = fmaf(hv.w, Uc[4 * k + 3], a3);
            }
            float z = (a0 + a1) + (a2 + a3);
            // Apply this gate's sigmoid distributedly (all 256 threads).
            a_lds[g] = fast_sigmoid(z);
            __syncthreads();
            if (g < Hn) {
                float ai = a_lds[g];
                float af = a_lds[g + Hn];
                float ag = a_lds[g + 2 * Hn];
                float ao = a_lds[g + 3 * Hn];
                c = fmaf(af, c, ai * ag);
                h_lds[g] = ao * fast_sigmoid(c);
            }
            __syncthreads();
        }
    }

    // Heads: gamma = h.wg + bgam ; beta = h.wb + bbet  (wave 0 only)
    if (g < Hn) {
        float hg = h_lds[g];
        float vg = hg * wg[g];
        float vb = hg * wb[g];
#pragma unroll
        for (int off = 32; off > 0; off >>= 1) {
            vg += __shfl_xor(vg, off, 64);
            vb += __shfl_xor(vb, off, 64);
        }
        if (g == 0) {
            out[b]       = vg + bgam[0];
            out[Bsz + b] = vb + bbet[0];
        }
    }
}

extern "C" void kernel_launch(void* const* d_in, const int* in_sizes, int n_in,
                              void* d_out, int out_size, void* d_ws, size_t ws_size,
                              hipStream_t stream) {
    const float* x    = (const float*)d_in[0];
    // d_in[1] = inputs_state: only used for batch size in reference -> unused
    const float* W    = (const float*)d_in[2];
    const float* U    = (const float*)d_in[3];
    const float* bias = (const float*)d_in[4];
    const float* wg   = (const float*)d_in[5];
    const float* bgam = (const float*)d_in[6];
    const float* wb   = (const float*)d_in[7];
    const float* bbet = (const float*)d_in[8];
    float* out = (float*)d_out;

    lstm_film_kernel<<<Bsz, 256, 0, stream>>>(x, W, U, bias, wg, bgam, wb, bbet, out);
}

// Round 2
// 1026.312 us; speedup vs baseline: 1.7214x; 1.7214x over previous
//
#include <hip/hip_runtime.h>

// FiLM LSTM, two-phase:
//  Phase 1 (parallel): xz[b,t,:] = x[b,t,:] @ W + bias, stored f16 in d_ws,
//    laid out per-row as [j=0..63][q=0..3] (so recurrence lane j loads its 4
//    gate pre-activations with ONE dwordx2).
//  Phase 2 (serial over T): 256 blocks x 64 threads (1 wave, NO barriers).
//    Lane j owns h[j], c[j], computes all 4 of its gates with f16 dot2
//    (f32 accumulate). h broadcast via LDS within the wave (lgkmcnt only).
//  T is chunked if ws is small; h/c state carried in ws between launches.

typedef _Float16 f16;
typedef f16 f16x2 __attribute__((ext_vector_type(2)));
typedef f16 f16x4 __attribute__((ext_vector_type(4)));
typedef f16 f16x8 __attribute__((ext_vector_type(8)));

#ifndef __has_builtin
#define __has_builtin(x) 0
#endif

constexpr int Bsz = 256;
constexpr int Tn  = 2048;
constexpr int Dn  = 64;
constexpr int Hn  = 64;
constexpr int G4  = 256;   // 4*H

__device__ __forceinline__ float sigmoidf_fast(float z) {
    return __builtin_amdgcn_rcpf(1.0f + __expf(-z));
}

__device__ __forceinline__ float dot2acc(f16x2 a, f16x2 b, float acc) {
#if __has_builtin(__builtin_amdgcn_fdot2)
    return __builtin_amdgcn_fdot2(a, b, acc, false);
#else
    return acc + (float)a[0] * (float)b[0] + (float)a[1] * (float)b[1];
#endif
}

// ---------------- Phase 1: x @ W + b -> f16 ----------------
__global__ __launch_bounds__(256) void xproj_kernel(
    const float* __restrict__ x,     // [B,T,64]
    const float* __restrict__ W,     // [64,256]
    const float* __restrict__ bias,  // [256]
    f16* __restrict__ xz,            // [B*Tc, 256] chunk buffer
    int t0, int Tc, int rows_per_block)
{
    __shared__ __align__(16) f16 xs[16 * Dn];  // one 16-row tile, f16
    const int tid = threadIdx.x;
    // store index tid = j*4+q  ->  reference gate column g = q*64 + j
    const int g = (tid & 3) * 64 + (tid >> 2);

    f16x2 Wp[32];
#pragma unroll
    for (int k2 = 0; k2 < 32; ++k2) {
        Wp[k2][0] = (f16)W[(2 * k2 + 0) * G4 + g];
        Wp[k2][1] = (f16)W[(2 * k2 + 1) * G4 + g];
    }
    const float bg = bias[g];

    const int row0 = blockIdx.x * rows_per_block;   // chunk-row space [0, B*Tc)
    for (int rt = 0; rt < rows_per_block; rt += 16) {
        const int r = row0 + rt;                    // 16-row group, one batch
        const int b = r / Tc, tt = r % Tc;
        const float* xrow = x + ((size_t)b * Tn + t0 + tt) * Dn;
        float4 v = ((const float4*)xrow)[tid];      // 16 rows * 16 float4
        f16x4 h4;
        h4[0] = (f16)v.x; h4[1] = (f16)v.y; h4[2] = (f16)v.z; h4[3] = (f16)v.w;
        __syncthreads();                            // protect previous tile
        ((f16x4*)xs)[tid] = h4;
        __syncthreads();
#pragma unroll
        for (int rr = 0; rr < 16; ++rr) {
            const f16x8* xr = (const f16x8*)(xs + rr * Dn);
            float acc = bg;
#pragma unroll
            for (int kk = 0; kk < 8; ++kk) {
                f16x8 xv = xr[kk];
#pragma unroll
                for (int p = 0; p < 4; ++p) {
                    f16x2 xp; xp[0] = xv[2 * p]; xp[1] = xv[2 * p + 1];
                    acc = dot2acc(xp, Wp[kk * 4 + p], acc);
                }
            }
            xz[(size_t)(r + rr) * G4 + tid] = (f16)acc;
        }
    }
}

// ---------------- Phase 2: serial recurrence ----------------
__global__ __launch_bounds__(64) void lstm_rec_kernel(
    const f16* __restrict__ xz,      // [B, Tc, 256]
    const float* __restrict__ U,     // [64,256]
    float* __restrict__ hstate, float* __restrict__ cstate,  // [B,64] each
    const float* __restrict__ wg, const float* __restrict__ bgam,
    const float* __restrict__ wb, const float* __restrict__ bbet,
    float* __restrict__ out, int t0, int Tc, int is_last)
{
    __shared__ __align__(16) f16 hl[Hn];
    const int b = blockIdx.x, j = threadIdx.x;

    // U columns for this lane's 4 gates, packed f16 pairs (128 VGPRs)
    f16x2 Up[4][32];
#pragma unroll
    for (int q = 0; q < 4; ++q)
#pragma unroll
        for (int k2 = 0; k2 < 32; ++k2) {
            Up[q][k2][0] = (f16)U[(2 * k2 + 0) * G4 + q * 64 + j];
            Up[q][k2][1] = (f16)U[(2 * k2 + 1) * G4 + q * 64 + j];
        }

    float h, c;
    if (t0 == 0) { h = 0.0f; c = 0.0f; }
    else { h = hstate[b * Hn + j]; c = cstate[b * Hn + j]; }
    hl[j] = (f16)h;

    const f16* zb = xz + (size_t)b * Tc * G4 + j * 4;
    f16x4 zcur = *(const f16x4*)zb;

    for (int tt = 0; tt < Tc; ++tt) {
        f16x4 znext = (tt + 1 < Tc) ? *(const f16x4*)(zb + (size_t)(tt + 1) * G4)
                                    : zcur;
        float a0 = (float)zcur[0], a1 = (float)zcur[1];
        float a2 = (float)zcur[2], a3 = (float)zcur[3];
        const f16x8* hv = (const f16x8*)hl;
#pragma unroll
        for (int kk = 0; kk < 8; ++kk) {
            f16x8 hh = hv[kk];
#pragma unroll
            for (int p = 0; p < 4; ++p) {
                f16x2 hp; hp[0] = hh[2 * p]; hp[1] = hh[2 * p + 1];
                a0 = dot2acc(hp, Up[0][kk * 4 + p], a0);
                a1 = dot2acc(hp, Up[1][kk * 4 + p], a1);
                a2 = dot2acc(hp, Up[2][kk * 4 + p], a2);
                a3 = dot2acc(hp, Up[3][kk * 4 + p], a3);
            }
        }
        float gi = sigmoidf_fast(a0);
        float gf = sigmoidf_fast(a1);
        float gg = sigmoidf_fast(a2);
        float go = sigmoidf_fast(a3);
        c = fmaf(gf, c, gi * gg);
        h = go * sigmoidf_fast(c);
        hl[j] = (f16)h;          // in-order LDS: next iter's reads see it
        zcur = znext;
    }
    hstate[b * Hn + j] = h;
    cstate[b * Hn + j] = c;

    if (is_last) {
        float vg = h * wg[j], vb = h * wb[j];
#pragma unroll
        for (int off = 32; off > 0; off >>= 1) {
            vg += __shfl_xor(vg, off, 64);
            vb += __shfl_xor(vb, off, 64);
        }
        if (j == 0) {
            out[b] = vg + bgam[0];
            out[Bsz + b] = vb + bbet[0];
        }
    }
}

// ---------------- Fallback (round-1 fused) if ws too small ----------------
__global__ __launch_bounds__(256, 1) void lstm_film_fused(
    const float* __restrict__ x, const float* __restrict__ W,
    const float* __restrict__ U, const float* __restrict__ bias,
    const float* __restrict__ wg, const float* __restrict__ bgam,
    const float* __restrict__ wb, const float* __restrict__ bbet,
    float* __restrict__ out)
{
    __shared__ float xs[16 * Dn];
    __shared__ float h_lds[Hn];
    __shared__ float a_lds[G4];
    const int b = blockIdx.x, g = threadIdx.x;
    float Wc[Dn], Uc[Hn];
#pragma unroll
    for (int k = 0; k < Dn; ++k) Wc[k] = W[k * G4 + g];
#pragma unroll
    for (int k = 0; k < Hn; ++k) Uc[k] = U[k * G4 + g];
    const float bg = bias[g];
    float c = 0.0f;
    if (g < Hn) h_lds[g] = 0.0f;
    const float* xb = x + (size_t)b * Tn * Dn;
    float4 xreg = ((const float4*)xb)[g];
    for (int t0 = 0; t0 < Tn; t0 += 16) {
        ((float4*)xs)[g] = xreg;
        __syncthreads();
        if (t0 + 16 < Tn) xreg = ((const float4*)(xb + (size_t)(t0 + 16) * Dn))[g];
        for (int tt = 0; tt < 16; ++tt) {
            const float4* xt = (const float4*)(xs + tt * Dn);
            const float4* hv4 = (const float4*)h_lds;
            float a0 = bg, a1 = 0.f, a2 = 0.f, a3 = 0.f;
#pragma unroll
            for (int k = 0; k < 16; ++k) {
                float4 xv = xt[k];
                a0 = fmaf(xv.x, Wc[4 * k + 0], a0);
                a1 = fmaf(xv.y, Wc[4 * k + 1], a1);
                a2 = fmaf(xv.z, Wc[4 * k + 2], a2);
                a3 = fmaf(xv.w, Wc[4 * k + 3], a3);
            }
#pragma unroll
            for (int k = 0; k < 16; ++k) {
                float4 hv = hv4[k];
                a0 = fmaf(hv.x, Uc[4 * k + 0], a0);
                a1 = fmaf(hv.y, Uc[4 * k + 1], a1);
                a2 = fmaf(hv.z, Uc[4 * k + 2], a2);
                a3 = fmaf(hv.w, Uc[4 * k + 3], a3);
            }
            float z = (a0 + a1) + (a2 + a3);
            a_lds[g] = sigmoidf_fast(z);
            __syncthreads();
            if (g < Hn) {
                float ai = a_lds[g], af = a_lds[g + 64];
                float ag = a_lds[g + 128], ao = a_lds[g + 192];
                c = fmaf(af, c, ai * ag);
                h_lds[g] = ao * sigmoidf_fast(c);
            }
            __syncthreads();
        }
    }
    if (g < Hn) {
        float hg = h_lds[g];
        float vg = hg * wg[g], vb = hg * wb[g];
#pragma unroll
        for (int off = 32; off > 0; off >>= 1) {
            vg += __shfl_xor(vg, off, 64);
            vb += __shfl_xor(vb, off, 64);
        }
        if (g == 0) { out[b] = vg + bgam[0]; out[Bsz + b] = vb + bbet[0]; }
    }
}

extern "C" void kernel_launch(void* const* d_in, const int* in_sizes, int n_in,
                              void* d_out, int out_size, void* d_ws, size_t ws_size,
                              hipStream_t stream) {
    const float* x    = (const float*)d_in[0];
    const float* W    = (const float*)d_in[2];
    const float* U    = (const float*)d_in[3];
    const float* bias = (const float*)d_in[4];
    const float* wg   = (const float*)d_in[5];
    const float* bgam = (const float*)d_in[6];
    const float* wb   = (const float*)d_in[7];
    const float* bbet = (const float*)d_in[8];
    float* out = (float*)d_out;

    char* ws = (char*)d_ws;
    float* hstate = (float*)ws;                 // 64 KB
    float* cstate = (float*)(ws + 65536);       // 64 KB
    f16*   xz     = (f16*)(ws + 131072);

    size_t avail = ws_size > 131072 ? ws_size - 131072 : 0;
    int Tc = 0;
    const int cands[7] = {2048, 1024, 512, 256, 128, 64, 32};
    for (int i = 0; i < 7; ++i) {
        size_t need = (size_t)Bsz * cands[i] * G4 * sizeof(f16);
        if (need <= avail) { Tc = cands[i]; break; }
    }
    if (Tc == 0) {
        lstm_film_fused<<<Bsz, 256, 0, stream>>>(x, W, U, bias, wg, bgam, wb, bbet, out);
        return;
    }

    for (int t0 = 0; t0 < Tn; t0 += Tc) {
        const int total_rows = Bsz * Tc;
        const int rpb = 128;                    // multiple of 16
        const int grid = total_rows / rpb;
        xproj_kernel<<<grid, 256, 0, stream>>>(x, W, bias, xz, t0, Tc, rpb);
        lstm_rec_kernel<<<Bsz, 64, 0, stream>>>(xz, U, hstate, cstate,
                                                wg, bgam, wb, bbet, out,
                                                t0, Tc, (t0 + Tc) == Tn);
    }
}

// Round 3
// 877.365 us; speedup vs baseline: 2.0137x; 1.1698x over previous
//
#include <hip/hip_runtime.h>

// FiLM LSTM, two-phase:
//  Phase 1 (parallel, per-wave tiles, no barriers): xz = x @ W + bias -> f16 ws
//    row layout [row][j*4+q] so recurrence lane j loads its 4 gates as one b64.
//  Phase 2 (serial over T): 256 blocks x 64 threads (1 wave, no barriers).
//    Lane j owns h[j],c[j]; f16 dot2 with f32 accum; h broadcast via LDS.
//    xz stream prefetched 4 steps deep (HBM latency ~900cyc < 4*step).

typedef _Float16 f16;
typedef f16 f16x2 __attribute__((ext_vector_type(2)));
typedef f16 f16x4 __attribute__((ext_vector_type(4)));
typedef f16 f16x8 __attribute__((ext_vector_type(8)));

#ifndef __has_builtin
#define __has_builtin(x) 0
#endif

constexpr int Bsz = 256;
constexpr int Tn  = 2048;
constexpr int Dn  = 64;
constexpr int Hn  = 64;
constexpr int G4  = 256;   // 4*H
constexpr int XS_STRIDE = 72;  // f16 elems per staged row (144B: 16B-aligned, debanked)

__device__ __forceinline__ float sigmoidf_fast(float z) {
    return __builtin_amdgcn_rcpf(1.0f + __expf(-z));
}

__device__ __forceinline__ float dot2acc(f16x2 a, f16x2 b, float acc) {
#if __has_builtin(__builtin_amdgcn_fdot2)
    return __builtin_amdgcn_fdot2(a, b, acc, false);
#else
    return acc + (float)a[0] * (float)b[0] + (float)a[1] * (float)b[1];
#endif
}

// ---------------- Phase 1: x @ W + b -> f16, per-wave 16-row tiles ----------
__global__ __launch_bounds__(256) void xproj_kernel(
    const float* __restrict__ x,     // [B,T,64]
    const float* __restrict__ W,     // [64,256]
    const float* __restrict__ bias,  // [256]
    f16* __restrict__ xz,            // [B*Tc, 256]
    int t0, int Tc, int tiles_per_wave)
{
    __shared__ __align__(16) f16 xs[4][16 * XS_STRIDE];
    const int tid  = threadIdx.x;
    const int wave = tid >> 6;
    const int j    = tid & 63;

    // lane j owns gate columns q*64+j, q=0..3, packed f16 pairs (128 VGPRs)
    f16x2 Wp[4][32];
#pragma unroll
    for (int q = 0; q < 4; ++q)
#pragma unroll
        for (int k2 = 0; k2 < 32; ++k2) {
            Wp[q][k2][0] = (f16)W[(2 * k2 + 0) * G4 + q * 64 + j];
            Wp[q][k2][1] = (f16)W[(2 * k2 + 1) * G4 + q * 64 + j];
        }
    float bg[4];
#pragma unroll
    for (int q = 0; q < 4; ++q) bg[q] = bias[q * 64 + j];

    f16* xsw = xs[wave];
    const int jhi = j >> 4, jlo = j & 15;

    for (int it = 0; it < tiles_per_wave; ++it) {
        const int tile = (blockIdx.x * 4 + wave) * tiles_per_wave + it;
        const int r0 = tile * 16;                 // chunk-row space [0, B*Tc)
        const int b = r0 / Tc, ttl = r0 % Tc;
        const float* xrow = x + ((size_t)b * Tn + t0 + ttl) * Dn;
        // stage 16 rows (f32 -> f16) : 4 passes of 4 rows
#pragma unroll
        for (int p = 0; p < 4; ++p) {
            const int r16 = p * 4 + jhi;
            float4 v = ((const float4*)(xrow + r16 * Dn))[jlo];
            f16x4 h4; h4[0] = (f16)v.x; h4[1] = (f16)v.y; h4[2] = (f16)v.z; h4[3] = (f16)v.w;
            *(f16x4*)(xsw + r16 * XS_STRIDE + jlo * 4) = h4;
        }
        // in-wave LDS ordering: no barrier needed
#pragma unroll
        for (int rr = 0; rr < 16; ++rr) {
            const f16x8* xr = (const f16x8*)(xsw + rr * XS_STRIDE);
            float a0 = bg[0], a1 = bg[1], a2 = bg[2], a3 = bg[3];
#pragma unroll
            for (int kk = 0; kk < 8; ++kk) {
                f16x8 xv = xr[kk];
#pragma unroll
                for (int p = 0; p < 4; ++p) {
                    f16x2 xp; xp[0] = xv[2 * p]; xp[1] = xv[2 * p + 1];
                    a0 = dot2acc(xp, Wp[0][kk * 4 + p], a0);
                    a1 = dot2acc(xp, Wp[1][kk * 4 + p], a1);
                    a2 = dot2acc(xp, Wp[2][kk * 4 + p], a2);
                    a3 = dot2acc(xp, Wp[3][kk * 4 + p], a3);
                }
            }
            f16x4 o; o[0] = (f16)a0; o[1] = (f16)a1; o[2] = (f16)a2; o[3] = (f16)a3;
            *(f16x4*)(xz + (size_t)(r0 + rr) * G4 + j * 4) = o;
        }
    }
}

// ---------------- Phase 2: serial recurrence, 4-deep z prefetch ------------
__global__ __launch_bounds__(64) void lstm_rec_kernel(
    const f16* __restrict__ xz,      // [B, Tc, 256]
    const float* __restrict__ U,     // [64,256]
    float* __restrict__ hstate, float* __restrict__ cstate,  // [B,64] each
    const float* __restrict__ wg, const float* __restrict__ bgam,
    const float* __restrict__ wb, const float* __restrict__ bbet,
    float* __restrict__ out, int t0, int Tc, int is_last)
{
    __shared__ __align__(16) f16 hl[Hn];
    const int b = blockIdx.x, j = threadIdx.x;

    f16x2 Up[4][32];
#pragma unroll
    for (int q = 0; q < 4; ++q)
#pragma unroll
        for (int k2 = 0; k2 < 32; ++k2) {
            Up[q][k2][0] = (f16)U[(2 * k2 + 0) * G4 + q * 64 + j];
            Up[q][k2][1] = (f16)U[(2 * k2 + 1) * G4 + q * 64 + j];
        }

    float h, c;
    if (t0 == 0) { h = 0.0f; c = 0.0f; }
    else { h = hstate[b * Hn + j]; c = cstate[b * Hn + j]; }
    hl[j] = (f16)h;

    const f16* zb = xz + (size_t)b * Tc * G4 + j * 4;
    const int tmax = Tc - 1;
#define ZLD(T) (*(const f16x4*)(zb + (size_t)(T) * G4))
    f16x4 z0 = ZLD(0);
    f16x4 z1 = ZLD(1 < tmax ? 1 : tmax);
    f16x4 z2 = ZLD(2 < tmax ? 2 : tmax);
    f16x4 z3 = ZLD(3 < tmax ? 3 : tmax);

#define LSTM_STEP(ZR, TPF) do {                                               \
        float a0 = (float)ZR[0], a1 = (float)ZR[1];                           \
        float a2 = (float)ZR[2], a3 = (float)ZR[3];                           \
        {   int tpf = (TPF); tpf = tpf < tmax ? tpf : tmax;                   \
            ZR = ZLD(tpf); }                                                  \
        const f16x8* hv = (const f16x8*)hl;                                   \
        _Pragma("unroll")                                                     \
        for (int kk = 0; kk < 8; ++kk) {                                      \
            f16x8 hh = hv[kk];                                                \
            _Pragma("unroll")                                                 \
            for (int p = 0; p < 4; ++p) {                                     \
                f16x2 hp; hp[0] = hh[2 * p]; hp[1] = hh[2 * p + 1];           \
                a0 = dot2acc(hp, Up[0][kk * 4 + p], a0);                      \
                a1 = dot2acc(hp, Up[1][kk * 4 + p], a1);                      \
                a2 = dot2acc(hp, Up[2][kk * 4 + p], a2);                      \
                a3 = dot2acc(hp, Up[3][kk * 4 + p], a3);                      \
            }                                                                 \
        }                                                                     \
        float gi = sigmoidf_fast(a0);                                         \
        float gf = sigmoidf_fast(a1);                                         \
        float gg = sigmoidf_fast(a2);                                         \
        float go = sigmoidf_fast(a3);                                         \
        c = fmaf(gf, c, gi * gg);                                             \
        h = go * sigmoidf_fast(c);                                            \
        hl[j] = (f16)h;                                                       \
    } while (0)

    for (int tt = 0; tt < Tc; tt += 4) {
        LSTM_STEP(z0, tt + 4);
        LSTM_STEP(z1, tt + 5);
        LSTM_STEP(z2, tt + 6);
        LSTM_STEP(z3, tt + 7);
    }
#undef LSTM_STEP
#undef ZLD

    hstate[b * Hn + j] = h;
    cstate[b * Hn + j] = c;

    if (is_last) {
        float vg = h * wg[j], vb = h * wb[j];
#pragma unroll
        for (int off = 32; off > 0; off >>= 1) {
            vg += __shfl_xor(vg, off, 64);
            vb += __shfl_xor(vb, off, 64);
        }
        if (j == 0) {
            out[b] = vg + bgam[0];
            out[Bsz + b] = vb + bbet[0];
        }
    }
}

// ---------------- Fallback (fused) if ws too small ----------------
__global__ __launch_bounds__(256, 1) void lstm_film_fused(
    const float* __restrict__ x, const float* __restrict__ W,
    const float* __restrict__ U, const float* __restrict__ bias,
    const float* __restrict__ wg, const float* __restrict__ bgam,
    const float* __restrict__ wb, const float* __restrict__ bbet,
    float* __restrict__ out)
{
    __shared__ float xs[16 * Dn];
    __shared__ float h_lds[Hn];
    __shared__ float a_lds[G4];
    const int b = blockIdx.x, g = threadIdx.x;
    float Wc[Dn], Uc[Hn];
#pragma unroll
    for (int k = 0; k < Dn; ++k) Wc[k] = W[k * G4 + g];
#pragma unroll
    for (int k = 0; k < Hn; ++k) Uc[k] = U[k * G4 + g];
    const float bg = bias[g];
    float c = 0.0f;
    if (g < Hn) h_lds[g] = 0.0f;
    const float* xb = x + (size_t)b * Tn * Dn;
    float4 xreg = ((const float4*)xb)[g];
    for (int t0 = 0; t0 < Tn; t0 += 16) {
        ((float4*)xs)[g] = xreg;
        __syncthreads();
        if (t0 + 16 < Tn) xreg = ((const float4*)(xb + (size_t)(t0 + 16) * Dn))[g];
        for (int tt = 0; tt < 16; ++tt) {
            const float4* xt = (const float4*)(xs + tt * Dn);
            const float4* hv4 = (const float4*)h_lds;
            float a0 = bg, a1 = 0.f, a2 = 0.f, a3 = 0.f;
#pragma unroll
            for (int k = 0; k < 16; ++k) {
                float4 xv = xt[k];
                a0 = fmaf(xv.x, Wc[4 * k + 0], a0);
                a1 = fmaf(xv.y, Wc[4 * k + 1], a1);
                a2 = fmaf(xv.z, Wc[4 * k + 2], a2);
                a3 = fmaf(xv.w, Wc[4 * k + 3], a3);
            }
#pragma unroll
            for (int k = 0; k < 16; ++k) {
                float4 hv = hv4[k];
                a0 = fmaf(hv.x, Uc[4 * k + 0], a0);
                a1 = fmaf(hv.y, Uc[4 * k + 1], a1);
                a2 = fmaf(hv.z, Uc[4 * k + 2], a2);
                a3 = fmaf(hv.w, Uc[4 * k + 3], a3);
            }
            float z = (a0 + a1) + (a2 + a3);
            a_lds[g] = sigmoidf_fast(z);
            __syncthreads();
            if (g < Hn) {
                float ai = a_lds[g], af = a_lds[g + 64];
                float ag = a_lds[g + 128], ao = a_lds[g + 192];
                c = fmaf(af, c, ai * ag);
                h_lds[g] = ao * sigmoidf_fast(c);
            }
            __syncthreads();
        }
    }
    if (g < Hn) {
        float hg = h_lds[g];
        float vg = hg * wg[g], vb = hg * wb[g];
#pragma unroll
        for (int off = 32; off > 0; off >>= 1) {
            vg += __shfl_xor(vg, off, 64);
            vb += __shfl_xor(vb, off, 64);
        }
        if (g == 0) { out[b] = vg + bgam[0]; out[Bsz + b] = vb + bbet[0]; }
    }
}

extern "C" void kernel_launch(void* const* d_in, const int* in_sizes, int n_in,
                              void* d_out, int out_size, void* d_ws, size_t ws_size,
                              hipStream_t stream) {
    const float* x    = (const float*)d_in[0];
    const float* W    = (const float*)d_in[2];
    const float* U    = (const float*)d_in[3];
    const float* bias = (const float*)d_in[4];
    const float* wg   = (const float*)d_in[5];
    const float* bgam = (const float*)d_in[6];
    const float* wb   = (const float*)d_in[7];
    const float* bbet = (const float*)d_in[8];
    float* out = (float*)d_out;

    char* ws = (char*)d_ws;
    float* hstate = (float*)ws;                 // 64 KB
    float* cstate = (float*)(ws + 65536);       // 64 KB
    f16*   xz     = (f16*)(ws + 131072);

    size_t avail = ws_size > 131072 ? ws_size - 131072 : 0;
    int Tc = 0;
    const int cands[7] = {2048, 1024, 512, 256, 128, 64, 32};
    for (int i = 0; i < 7; ++i) {
        size_t need = (size_t)Bsz * cands[i] * G4 * sizeof(f16);
        if (need <= avail) { Tc = cands[i]; break; }
    }
    if (Tc == 0) {
        lstm_film_fused<<<Bsz, 256, 0, stream>>>(x, W, U, bias, wg, bgam, wb, bbet, out);
        return;
    }

    for (int t0 = 0; t0 < Tn; t0 += Tc) {
        const int total_rows = Bsz * Tc;          // multiple of 256
        const int tiles_per_wave = 4;             // 16-row tiles per wave
        const int rows_per_block = 4 * tiles_per_wave * 16;  // 256
        const int grid = total_rows / rows_per_block;
        xproj_kernel<<<grid, 256, 0, stream>>>(x, W, bias, xz, t0, Tc, tiles_per_wave);
        lstm_rec_kernel<<<Bsz, 64, 0, stream>>>(xz, U, hstate, cstate,
                                                wg, bgam, wb, bbet, out,
                                                t0, Tc, (t0 + Tc) == Tn);
    }
}

// Round 4
// 784.348 us; speedup vs baseline: 2.2525x; 1.1186x over previous
//
#include <hip/hip_runtime.h>

// FiLM LSTM, fused producer/consumer (one kernel, no workspace):
//   256 blocks (1 batch each) x 128 threads (2 waves).
//   wave 1 (producer): z_t = x_t @ W + bias -> f16x4 {i,f,g,o} per unit j,
//     written to LDS double buffer, 32 timesteps per chunk.
//   wave 0 (consumer): serial LSTM recurrence; lane j owns h[j], c[j];
//     h broadcast via LDS (in-wave ordering, no barrier); f16 dot2, f32 accum.
//   Sync: one __syncthreads per 32-step chunk (barrier counts match exactly).

typedef _Float16 f16;
typedef f16 f16x2 __attribute__((ext_vector_type(2)));
typedef f16 f16x4 __attribute__((ext_vector_type(4)));

#ifndef __has_builtin
#define __has_builtin(x) 0
#endif

constexpr int Bsz = 256;
constexpr int Tn  = 2048;
constexpr int Dn  = 64;
constexpr int Hn  = 64;
constexpr int G4  = 256;           // 4*H
constexpr int CHS = 32;            // timesteps per chunk
constexpr int NC  = Tn / CHS;      // 64 chunks
constexpr int XSTR = 72;           // f16 elems per staged x row (144B, 16B-aligned)

__device__ __forceinline__ float sigmoidf_fast(float z) {
    return __builtin_amdgcn_rcpf(1.0f + __expf(-z));
}

__device__ __forceinline__ float dot2acc(f16x2 a, f16x2 b, float acc) {
#if __has_builtin(__builtin_amdgcn_fdot2)
    return __builtin_amdgcn_fdot2(a, b, acc, false);
#else
    return acc + (float)a[0] * (float)b[0] + (float)a[1] * (float)b[1];
#endif
}

__device__ __forceinline__ f16x2 asf16x2(unsigned int u) {
    union { unsigned int u; f16x2 h; } v; v.u = u; return v.h;
}

__global__ __launch_bounds__(128, 1) void lstm_film_fused(
    const float* __restrict__ x,     // [B,T,64]
    const float* __restrict__ W,     // [64,256]
    const float* __restrict__ U,     // [64,256]
    const float* __restrict__ bias,  // [256]
    const float* __restrict__ wg, const float* __restrict__ bgam,
    const float* __restrict__ wb, const float* __restrict__ bbet,
    float* __restrict__ out)         // gamma[256] then beta[256]
{
    __shared__ f16x4 zbuf[2][CHS][Hn];              // 32 KiB
    __shared__ __align__(16) f16 hl[Hn];            // 128 B
    __shared__ __align__(16) f16 xstage[CHS * XSTR];// 4.5 KiB

    const int wave = threadIdx.x >> 6;
    const int j    = threadIdx.x & 63;
    const int b    = blockIdx.x;
    const float* xb = x + (size_t)b * Tn * Dn;

    if (wave == 1) {
        // ------------------- producer -------------------
        f16x2 Wp[4][32];
        float bg[4];
#pragma unroll
        for (int q = 0; q < 4; ++q) {
#pragma unroll
            for (int k2 = 0; k2 < 32; ++k2) {
                Wp[q][k2][0] = (f16)W[(2 * k2 + 0) * G4 + q * 64 + j];
                Wp[q][k2][1] = (f16)W[(2 * k2 + 1) * G4 + q * 64 + j];
            }
            bg[q] = bias[q * 64 + j];
        }
        const int row0 = j >> 4, part = j & 15;     // 8 rows/lane-group, 16 parts

        float4 xld[8];                              // chunk 0 loads
#pragma unroll
        for (int p = 0; p < 8; ++p)
            xld[p] = ((const float4*)(xb + (size_t)(p * 4 + row0) * Dn))[part];

        for (int ch = 0; ch < NC; ++ch) {
            // stage chunk ch's x as f16 (waits on xld arrival)
#pragma unroll
            for (int p = 0; p < 8; ++p) {
                float4 v = xld[p];
                f16x4 o;
                o[0] = (f16)v.x; o[1] = (f16)v.y; o[2] = (f16)v.z; o[3] = (f16)v.w;
                *(f16x4*)(xstage + (p * 4 + row0) * XSTR + part * 4) = o;
            }
            // issue next chunk's global loads (latency hidden under dots)
            if (ch + 1 < NC) {
#pragma unroll
                for (int p = 0; p < 8; ++p)
                    xld[p] = ((const float4*)(xb +
                        (size_t)((ch + 1) * CHS + p * 4 + row0) * Dn))[part];
            }
            // dots: z = x_t @ W + b for 32 steps
#pragma unroll 1
            for (int s = 0; s < CHS; ++s) {
                const uint4* xr = (const uint4*)(xstage + s * XSTR);
                float a0 = bg[0], a1 = bg[1], a2 = bg[2], a3 = bg[3];
#pragma unroll
                for (int kk = 0; kk < 8; ++kk) {
                    uint4 w4 = xr[kk];
                    f16x2 p0 = asf16x2(w4.x), p1 = asf16x2(w4.y);
                    f16x2 p2 = asf16x2(w4.z), p3 = asf16x2(w4.w);
                    a0 = dot2acc(p0, Wp[0][kk * 4 + 0], a0);
                    a1 = dot2acc(p0, Wp[1][kk * 4 + 0], a1);
                    a2 = dot2acc(p0, Wp[2][kk * 4 + 0], a2);
                    a3 = dot2acc(p0, Wp[3][kk * 4 + 0], a3);
                    a0 = dot2acc(p1, Wp[0][kk * 4 + 1], a0);
                    a1 = dot2acc(p1, Wp[1][kk * 4 + 1], a1);
                    a2 = dot2acc(p1, Wp[2][kk * 4 + 1], a2);
                    a3 = dot2acc(p1, Wp[3][kk * 4 + 1], a3);
                    a0 = dot2acc(p2, Wp[0][kk * 4 + 2], a0);
                    a1 = dot2acc(p2, Wp[1][kk * 4 + 2], a1);
                    a2 = dot2acc(p2, Wp[2][kk * 4 + 2], a2);
                    a3 = dot2acc(p2, Wp[3][kk * 4 + 2], a3);
                    a0 = dot2acc(p3, Wp[0][kk * 4 + 3], a0);
                    a1 = dot2acc(p3, Wp[1][kk * 4 + 3], a1);
                    a2 = dot2acc(p3, Wp[2][kk * 4 + 3], a2);
                    a3 = dot2acc(p3, Wp[3][kk * 4 + 3], a3);
                }
                f16x4 zo;
                zo[0] = (f16)a0; zo[1] = (f16)a1; zo[2] = (f16)a2; zo[3] = (f16)a3;
                zbuf[ch & 1][s][j] = zo;
            }
            __syncthreads();
        }
    } else {
        // ------------------- consumer -------------------
        f16x2 Up[4][32];
#pragma unroll
        for (int q = 0; q < 4; ++q)
#pragma unroll
            for (int k2 = 0; k2 < 32; ++k2) {
                Up[q][k2][0] = (f16)U[(2 * k2 + 0) * G4 + q * 64 + j];
                Up[q][k2][1] = (f16)U[(2 * k2 + 1) * G4 + q * 64 + j];
            }
        const float wgj = wg[j], wbj = wb[j];
        const float bg0 = bgam[0], bb0 = bbet[0];

        float h = 0.0f, cc = 0.0f;
        hl[j] = (f16)0.0f;

        auto consume = [&](int chk) {
            const int bb2 = chk & 1;
            f16x4 zc = zbuf[bb2][0][j];
#pragma unroll 1
            for (int s = 0; s < CHS; ++s) {
                f16x4 zn = zbuf[bb2][(s + 1 < CHS) ? s + 1 : CHS - 1][j];
                float a0 = (float)zc[0], a1 = (float)zc[1];
                float a2 = (float)zc[2], a3 = (float)zc[3];
                const uint4* hv = (const uint4*)hl;
#pragma unroll
                for (int kk = 0; kk < 8; ++kk) {
                    uint4 w4 = hv[kk];
                    f16x2 p0 = asf16x2(w4.x), p1 = asf16x2(w4.y);
                    f16x2 p2 = asf16x2(w4.z), p3 = asf16x2(w4.w);
                    a0 = dot2acc(p0, Up[0][kk * 4 + 0], a0);
                    a1 = dot2acc(p0, Up[1][kk * 4 + 0], a1);
                    a2 = dot2acc(p0, Up[2][kk * 4 + 0], a2);
                    a3 = dot2acc(p0, Up[3][kk * 4 + 0], a3);
                    a0 = dot2acc(p1, Up[0][kk * 4 + 1], a0);
                    a1 = dot2acc(p1, Up[1][kk * 4 + 1], a1);
                    a2 = dot2acc(p1, Up[2][kk * 4 + 1], a2);
                    a3 = dot2acc(p1, Up[3][kk * 4 + 1], a3);
                    a0 = dot2acc(p2, Up[0][kk * 4 + 2], a0);
                    a1 = dot2acc(p2, Up[1][kk * 4 + 2], a1);
                    a2 = dot2acc(p2, Up[2][kk * 4 + 2], a2);
                    a3 = dot2acc(p2, Up[3][kk * 4 + 2], a3);
                    a0 = dot2acc(p3, Up[0][kk * 4 + 3], a0);
                    a1 = dot2acc(p3, Up[1][kk * 4 + 3], a1);
                    a2 = dot2acc(p3, Up[2][kk * 4 + 3], a2);
                    a3 = dot2acc(p3, Up[3][kk * 4 + 3], a3);
                }
                float gi = sigmoidf_fast(a0);
                float gf = sigmoidf_fast(a1);
                float gg = sigmoidf_fast(a2);
                float go = sigmoidf_fast(a3);
                cc = fmaf(gf, cc, gi * gg);
                h = go * sigmoidf_fast(cc);
                hl[j] = (f16)h;          // in-wave order: next step's reads see it
                zc = zn;
            }
        };

        __syncthreads();                 // matches producer's ch=0 barrier
        for (int ch = 1; ch < NC; ++ch) {
            consume(ch - 1);
            __syncthreads();             // matches producer's ch barrier
        }
        consume(NC - 1);

        // heads
        float vg = h * wgj, vb = h * wbj;
#pragma unroll
        for (int off = 32; off > 0; off >>= 1) {
            vg += __shfl_xor(vg, off, 64);
            vb += __shfl_xor(vb, off, 64);
        }
        if (j == 0) {
            out[b]       = vg + bg0;
            out[Bsz + b] = vb + bb0;
        }
    }
}

extern "C" void kernel_launch(void* const* d_in, const int* in_sizes, int n_in,
                              void* d_out, int out_size, void* d_ws, size_t ws_size,
                              hipStream_t stream) {
    const float* x    = (const float*)d_in[0];
    const float* W    = (const float*)d_in[2];
    const float* U    = (const float*)d_in[3];
    const float* bias = (const float*)d_in[4];
    const float* wg   = (const float*)d_in[5];
    const float* bgam = (const float*)d_in[6];
    const float* wb   = (const float*)d_in[7];
    const float* bbet = (const float*)d_in[8];
    float* out = (float*)d_out;

    lstm_film_fused<<<Bsz, 128, 0, stream>>>(x, W, U, bias, wg, bgam, wb, bbet, out);
}